// Round 5
// baseline (58.359 us; speedup 1.0000x reference)
//
#include <hip/hip_runtime.h>
#include <hip/hip_fp16.h>

// DeformConv2d: x[8,64,56,56], offset[8,18,56,56], weight[64,64,3,3] -> out[8,64,56,56]
// NHWC-fp16 x; single-phase register-resident gather + fp16 MFMA.

typedef _Float16 f16x8 __attribute__((ext_vector_type(8)));
typedef float    f32x4 __attribute__((ext_vector_type(4)));

namespace {
constexpr int Bn = 8, Cn = 64, Hn = 56, Wn = 56;
constexpr int Kk = 9, OCn = 64;
constexpr int NPIX = 56 * 56;      // 3136
constexpr int CK   = Cn * Kk;      // 576
constexpr int TPB  = 32;           // px per block
constexpr int TILES = NPIX / TPB;  // 98
constexpr int XTILES = NPIX / 64;  // 49
}

__device__ __forceinline__ __half2 u2h(unsigned u) {
    union { unsigned u; __half2 h; } x; x.u = u; return x.h;
}
__device__ __forceinline__ unsigned bcast_h(float f) {
    unsigned short hs = __half_as_ushort(__float2half(f));
    return (unsigned)hs * 0x10001u;
}

// Fused prep: blocks [0,392): x NCHW fp32 -> NHWC fp16 (64hw x 64c LDS transpose tile).
//             blocks [392,536): weight [OC][C][K] fp32 -> fp16 [oc][k*64+c].
__global__ __launch_bounds__(256) void prep_kernel(
    const float* __restrict__ x, const float* __restrict__ w,
    unsigned short* __restrict__ xh, unsigned short* __restrict__ wh)
{
    const int tid = threadIdx.x;
    if (blockIdx.x >= 392) {
        const int i = (blockIdx.x - 392) * 256 + tid;
        if (i < OCn * CK) {
            const int oc = i / CK, r = i % CK;
            const int c = r / Kk, k = r % Kk;
            wh[oc * CK + k * Cn + c] = __half_as_ushort(__float2half(w[i]));
        }
        return;
    }
    __shared__ unsigned short lds[64][66];
    const int b  = blockIdx.x / XTILES;
    const int t0 = (blockIdx.x % XTILES) * 64;
    const float* xb = x + (size_t)b * Cn * NPIX;
    {
        const int hw0 = (tid & 15) * 4;
        #pragma unroll
        for (int i = 0; i < 4; ++i) {
            const int c = (tid >> 4) + i * 16;
            const float4 v = *(const float4*)(xb + (size_t)c * NPIX + t0 + hw0);
            lds[hw0 + 0][c] = __half_as_ushort(__float2half(v.x));
            lds[hw0 + 1][c] = __half_as_ushort(__float2half(v.y));
            lds[hw0 + 2][c] = __half_as_ushort(__float2half(v.z));
            lds[hw0 + 3][c] = __half_as_ushort(__float2half(v.w));
        }
    }
    __syncthreads();
    {
        const int co = (tid & 7) * 8;
        #pragma unroll
        for (int i = 0; i < 2; ++i) {
            const int hw = (tid >> 3) + i * 32;
            unsigned short tmp[8] __attribute__((aligned(16)));
            #pragma unroll
            for (int j = 0; j < 8; ++j) tmp[j] = lds[hw][co + j];
            *(uint4*)(xh + ((size_t)b * NPIX + t0 + hw) * Cn + co) = *(const uint4*)tmp;
        }
    }
}

__global__ __launch_bounds__(256) void deform_kernel(
    const unsigned short* __restrict__ xh, const float* __restrict__ off,
    const unsigned short* __restrict__ wh, float* __restrict__ out)
{
    __shared__ uint4 smpw[Kk * TPB];   // per (k,pxr): 4 bilinear weights, broadcast half2
    __shared__ int4  smpa[Kk * TPB];   // per (k,pxr): 4 corner offsets, pre-scaled by Cn

    const int tid = threadIdx.x;
    const int b  = blockIdx.x / TILES;
    const int p0 = (blockIdx.x % TILES) * TPB;
    const unsigned short* xb = xh + (size_t)b * NPIX * Cn;
    const float* offb = off + (size_t)b * 18 * NPIX;

    // ---- metadata: one entry per (k, pxr), 288 entries ----
    for (int t = tid; t < Kk * TPB; t += 256) {
        const int k   = t >> 5;
        const int pxr = t & 31;
        const int p  = p0 + pxr;
        const int oy = p / Wn, ox = p % Wn;
        const int ki = k / 3, kj = k % 3;
        const float offy = offb[(size_t)(2 * k)     * NPIX + p];
        const float offx = offb[(size_t)(2 * k + 1) * NPIX + p];
        const float py  = offy + (float)(oy - 1 + ki);
        const float pxv = offx + (float)(ox - 1 + kj);
        const float y0f = floorf(py), x0f = floorf(pxv);
        const float ty = py - y0f, tx = pxv - x0f;
        const int y0 = (int)y0f, x0 = (int)x0f;
        const int y1 = y0 + 1, x1 = x0 + 1;
        const bool vy0 = (y0 >= 0) & (y0 < Hn);
        const bool vy1 = (y1 >= 0) & (y1 < Hn);
        const bool vx0 = (x0 >= 0) & (x0 < Wn);
        const bool vx1 = (x1 >= 0) & (x1 < Wn);
        const int cy0 = min(max(y0, 0), Hn - 1);
        const int cy1 = min(max(y1, 0), Hn - 1);
        const int cx0 = min(max(x0, 0), Wn - 1);
        const int cx1 = min(max(x1, 0), Wn - 1);
        uint4 wq;
        wq.x = bcast_h((vy0 && vx0) ? (1.f - ty) * (1.f - tx) : 0.f);
        wq.y = bcast_h((vy0 && vx1) ? (1.f - ty) * tx         : 0.f);
        wq.z = bcast_h((vy1 && vx0) ? ty * (1.f - tx)         : 0.f);
        wq.w = bcast_h((vy1 && vx1) ? ty * tx                 : 0.f);
        int4 av;
        av.x = (cy0 * Wn + cx0) * Cn;
        av.y = (cy0 * Wn + cx1) * Cn;
        av.z = (cy1 * Wn + cx0) * Cn;
        av.w = (cy1 * Wn + cx1) * Cn;
        smpw[t] = wq;
        smpa[t] = av;
    }
    __syncthreads();

    // ---- single phase: wave = 16px x 32oc; gather B to regs, MFMA inline ----
    const int lane = tid & 63;
    const int w    = tid >> 6;
    const int h    = w >> 1;        // px half (0/1)
    const int o    = w & 1;         // oc half (0/1)
    const int lr   = lane & 15;     // A row (oc) / B,D col (px)
    const int hi   = lane >> 4;     // k-octet group
    const int pxr  = h * 16 + lr;

    const unsigned short* wr0 = wh + (size_t)(o * 32 + lr) * CK + hi * 8;
    const unsigned short* wr1 = wr0 + (size_t)16 * CK;

    f32x4 acc0 = {0.f, 0.f, 0.f, 0.f};
    f32x4 acc1 = {0.f, 0.f, 0.f, 0.f};

    #pragma unroll
    for (int t = 0; t < Kk; ++t) {
        const uint4 wq = smpw[t * 32 + pxr];
        const int4  av = smpa[t * 32 + pxr];
        const __half2 w00 = u2h(wq.x), w01 = u2h(wq.y), w10 = u2h(wq.z), w11 = u2h(wq.w);
        #pragma unroll
        for (int sub = 0; sub < 2; ++sub) {
            const int kk = t * 2 + sub;
            const int c0 = sub * 32 + hi * 8;     // channel base within octet layout
            const uint4 s00 = *(const uint4*)(xb + av.x + c0);
            const uint4 s01 = *(const uint4*)(xb + av.y + c0);
            const uint4 s10 = *(const uint4*)(xb + av.z + c0);
            const uint4 s11 = *(const uint4*)(xb + av.w + c0);
            union { unsigned u[4]; f16x8 v; } bb;
            #pragma unroll
            for (int j = 0; j < 4; ++j) {
                __half2 a = __hmul2(w00, u2h(((const unsigned*)&s00)[j]));
                a = __hfma2(w01, u2h(((const unsigned*)&s01)[j]), a);
                a = __hfma2(w10, u2h(((const unsigned*)&s10)[j]), a);
                a = __hfma2(w11, u2h(((const unsigned*)&s11)[j]), a);
                bb.u[j] = *(const unsigned*)&a;
            }
            const f16x8 a0 = *(const f16x8*)(wr0 + kk * 32);
            const f16x8 a1 = *(const f16x8*)(wr1 + kk * 32);
            acc0 = __builtin_amdgcn_mfma_f32_16x16x32_f16(a0, bb.v, acc0, 0, 0, 0);
            acc1 = __builtin_amdgcn_mfma_f32_16x16x32_f16(a1, bb.v, acc1, 0, 0, 0);
        }
    }

    // D: col(px)=lane&15, row(oc within 16) = hi*4 + r
    float* ob = out + ((size_t)b * OCn + o * 32 + hi * 4) * NPIX + p0 + h * 16 + lr;
    #pragma unroll
    for (int r = 0; r < 4; ++r) {
        ob[(size_t)r * NPIX]        = acc0[r];
        ob[(size_t)(16 + r) * NPIX] = acc1[r];
    }
}

extern "C" void kernel_launch(void* const* d_in, const int* in_sizes, int n_in,
                              void* d_out, int out_size, void* d_ws, size_t ws_size,
                              hipStream_t stream) {
    const float* x   = (const float*)d_in[0];
    const float* off = (const float*)d_in[1];
    const float* w   = (const float*)d_in[2];
    float* out = (float*)d_out;
    unsigned short* wh = (unsigned short*)d_ws;                     // 73728 B
    unsigned short* xh = (unsigned short*)((char*)d_ws + 131072);   // 3.21 MB

    hipLaunchKernelGGL(prep_kernel, dim3(392 + 144), dim3(256), 0, stream, x, w, xh, wh);
    hipLaunchKernelGGL(deform_kernel, dim3(Bn * TILES), dim3(256), 0, stream,
                       xh, off, wh, out);
}

// Round 6
// 43.888 us; speedup vs baseline: 1.3297x; 1.3297x over previous
//
#include <hip/hip_runtime.h>
#include <hip/hip_fp16.h>

// DeformConv2d: x[8,64,56,56], offset[8,18,56,56], weight[64,64,3,3] -> out[8,64,56,56]
// NHWC-fp16 x; 3-phase deform kernel (metadata -> pipelined gather -> MFMA GEMM).

typedef _Float16 f16x8 __attribute__((ext_vector_type(8)));
typedef float    f32x4 __attribute__((ext_vector_type(4)));

namespace {
constexpr int Bn = 8, Cn = 64, Hn = 56, Wn = 56;
constexpr int Kk = 9, OCn = 64;
constexpr int NPIX = 56 * 56;      // 3136
constexpr int CK   = Cn * Kk;      // 576
constexpr int TPB  = 32;           // px per block
constexpr int TILES = NPIX / TPB;  // 98
constexpr int NTHR = 576;          // 9 waves
constexpr int KSTEPS = CK / 32;    // 18
constexpr int XTILES = NPIX / 64;  // 49
}

__device__ __forceinline__ __half2 u2h(unsigned u) {
    union { unsigned u; __half2 h; } x; x.u = u; return x.h;
}
__device__ __forceinline__ unsigned bcast_h(float f) {
    unsigned short hs = __half_as_ushort(__float2half(f));
    return (unsigned)hs * 0x10001u;
}

// Fused prep: blocks [0,392): x NCHW fp32 -> NHWC fp16 (64hw x 64c LDS transpose tile).
//             blocks [392,536): weight [OC][C][K] fp32 -> fp16 [oc][k*64+c].
__global__ __launch_bounds__(256) void prep_kernel(
    const float* __restrict__ x, const float* __restrict__ w,
    unsigned short* __restrict__ xh, unsigned short* __restrict__ wh)
{
    const int tid = threadIdx.x;
    if (blockIdx.x >= 392) {
        const int i = (blockIdx.x - 392) * 256 + tid;
        if (i < OCn * CK) {
            const int oc = i / CK, r = i % CK;
            const int c = r / Kk, k = r % Kk;
            wh[oc * CK + k * Cn + c] = __half_as_ushort(__float2half(w[i]));
        }
        return;
    }
    __shared__ unsigned short lds[64][66];
    const int b  = blockIdx.x / XTILES;
    const int t0 = (blockIdx.x % XTILES) * 64;
    const float* xb = x + (size_t)b * Cn * NPIX;
    {
        const int hw0 = (tid & 15) * 4;
        #pragma unroll
        for (int i = 0; i < 4; ++i) {
            const int c = (tid >> 4) + i * 16;
            const float4 v = *(const float4*)(xb + (size_t)c * NPIX + t0 + hw0);
            lds[hw0 + 0][c] = __half_as_ushort(__float2half(v.x));
            lds[hw0 + 1][c] = __half_as_ushort(__float2half(v.y));
            lds[hw0 + 2][c] = __half_as_ushort(__float2half(v.z));
            lds[hw0 + 3][c] = __half_as_ushort(__float2half(v.w));
        }
    }
    __syncthreads();
    {
        const int co = (tid & 7) * 8;
        #pragma unroll
        for (int i = 0; i < 2; ++i) {
            const int hw = (tid >> 3) + i * 32;
            unsigned short tmp[8] __attribute__((aligned(16)));
            #pragma unroll
            for (int j = 0; j < 8; ++j) tmp[j] = lds[hw][co + j];
            *(uint4*)(xh + ((size_t)b * NPIX + t0 + hw) * Cn + co) = *(const uint4*)tmp;
        }
    }
}

__global__ __launch_bounds__(NTHR, 6) void deform_kernel(
    const unsigned short* __restrict__ xh, const float* __restrict__ off,
    const unsigned short* __restrict__ wh, float* __restrict__ out)
{
    __shared__ uint4 smpw[Kk * TPB];   // 4608 B: bilinear weights, broadcast half2
    __shared__ int4  smpa[Kk * TPB];   // 4608 B: corner offsets pre-scaled by Cn
    __shared__ __align__(16) unsigned short v_lds[CK / 8][TPB][8];   // 36864 B

    const int tid = threadIdx.x;
    const int b  = blockIdx.x / TILES;
    const int p0 = (blockIdx.x % TILES) * TPB;
    const unsigned short* xb = xh + (size_t)b * NPIX * Cn;
    const float* offb = off + (size_t)b * 18 * NPIX;

    // ---- phase 0: metadata, one entry per (k, px), 288 entries ----
    if (tid < Kk * TPB) {
        const int k  = tid >> 5;
        const int px = tid & 31;
        const int p  = p0 + px;
        const int oy = p / Wn, ox = p % Wn;
        const int ki = k / 3, kj = k % 3;
        const float offy = offb[(size_t)(2 * k)     * NPIX + p];
        const float offx = offb[(size_t)(2 * k + 1) * NPIX + p];
        const float py  = offy + (float)(oy - 1 + ki);
        const float pxv = offx + (float)(ox - 1 + kj);
        const float y0f = floorf(py), x0f = floorf(pxv);
        const float ty = py - y0f, tx = pxv - x0f;
        const int y0 = (int)y0f, x0 = (int)x0f;
        const int y1 = y0 + 1, x1 = x0 + 1;
        const bool vy0 = (y0 >= 0) & (y0 < Hn);
        const bool vy1 = (y1 >= 0) & (y1 < Hn);
        const bool vx0 = (x0 >= 0) & (x0 < Wn);
        const bool vx1 = (x1 >= 0) & (x1 < Wn);
        const int cy0 = min(max(y0, 0), Hn - 1);
        const int cy1 = min(max(y1, 0), Hn - 1);
        const int cx0 = min(max(x0, 0), Wn - 1);
        const int cx1 = min(max(x1, 0), Wn - 1);
        uint4 wq;
        wq.x = bcast_h((vy0 && vx0) ? (1.f - ty) * (1.f - tx) : 0.f);
        wq.y = bcast_h((vy0 && vx1) ? (1.f - ty) * tx         : 0.f);
        wq.z = bcast_h((vy1 && vx0) ? ty * (1.f - tx)         : 0.f);
        wq.w = bcast_h((vy1 && vx1) ? ty * tx                 : 0.f);
        int4 av;
        av.x = (cy0 * Wn + cx0) * Cn;
        av.y = (cy0 * Wn + cx1) * Cn;
        av.z = (cy1 * Wn + cx0) * Cn;
        av.w = (cy1 * Wn + cx1) * Cn;
        smpw[tid] = wq;
        smpa[tid] = av;
    }
    __syncthreads();

    // ---- phase 1: gather, depth-2 software pipeline ----
    // unit u = g*64 + lane, g in [0,36): px = (lane&15)+(g&1)*16,
    // oct = (lane>>4)+((g>>1)&1)*4, k = g>>2. Each wave-load: 16 px x 4 oct
    // = 16 fully-used 64B lines. Thread handles g = g0 + 9*i, i = 0..3.
    {
        const int lane = tid & 63;
        const int g0   = tid >> 6;          // 0..8
        const int pxl  = lane & 15;
        const int octl = lane >> 4;         // 0..3

        uint4 wqr[2];
        uint4 s00[2], s01[2], s10[2], s11[2];
        int   vidx[2];

        auto stage = [&](int i, int sl) {
            const int g   = g0 + 9 * i;
            const int px  = pxl + (g & 1) * 16;
            const int oct = octl + ((g >> 1) & 1) * 4;
            const int k   = g >> 2;
            const int m   = k * TPB + px;
            const int4 av = smpa[m];
            const int co  = oct * 8;
            wqr[sl] = smpw[m];
            s00[sl] = *(const uint4*)(xb + av.x + co);
            s01[sl] = *(const uint4*)(xb + av.y + co);
            s10[sl] = *(const uint4*)(xb + av.z + co);
            s11[sl] = *(const uint4*)(xb + av.w + co);
            vidx[sl] = (k * 8 + oct) * TPB + px;
        };
        auto finish = [&](int sl) {
            const __half2 w00 = u2h(wqr[sl].x), w01 = u2h(wqr[sl].y);
            const __half2 w10 = u2h(wqr[sl].z), w11 = u2h(wqr[sl].w);
            unsigned res[4] __attribute__((aligned(16)));
            #pragma unroll
            for (int j = 0; j < 4; ++j) {
                __half2 a = __hmul2(w00, u2h(((const unsigned*)&s00[sl])[j]));
                a = __hfma2(w01, u2h(((const unsigned*)&s01[sl])[j]), a);
                a = __hfma2(w10, u2h(((const unsigned*)&s10[sl])[j]), a);
                a = __hfma2(w11, u2h(((const unsigned*)&s11[sl])[j]), a);
                res[j] = *(const unsigned*)&a;
            }
            *(uint4*)((unsigned short*)v_lds + (size_t)vidx[sl] * 8) = *(const uint4*)res;
        };

        stage(0, 0);
        stage(1, 1);
        finish(0);
        stage(2, 0);
        finish(1);
        stage(3, 1);
        finish(0);
        finish(1);
    }
    __syncthreads();

    // ---- phase 2: GEMM, waves 0..7 -> D[oc16-group][px16-half] ----
    if (tid < 512) {
        const int lane = tid & 63;
        const int w    = tid >> 6;
        const int og   = w & 3;        // oc 16-group
        const int ph   = w >> 2;       // px half
        const int lr   = lane & 15;    // A row (oc) / B,D col (px)
        const int hi   = lane >> 4;    // k-octet group
        const unsigned short* wr = wh + (size_t)(og * 16 + lr) * CK + hi * 8;
        f32x4 acc = {0.f, 0.f, 0.f, 0.f};
        #pragma unroll
        for (int kk = 0; kk < KSTEPS; ++kk) {
            const f16x8 a  = *(const f16x8*)(wr + kk * 32);
            const f16x8 bb = *(const f16x8*)(&v_lds[kk * 4 + hi][ph * 16 + lr][0]);
            acc = __builtin_amdgcn_mfma_f32_16x16x32_f16(a, bb, acc, 0, 0, 0);
        }
        float* ob = out + ((size_t)b * OCn + og * 16 + hi * 4) * NPIX + p0 + ph * 16 + lr;
        #pragma unroll
        for (int r = 0; r < 4; ++r) ob[(size_t)r * NPIX] = acc[r];
    }
}

extern "C" void kernel_launch(void* const* d_in, const int* in_sizes, int n_in,
                              void* d_out, int out_size, void* d_ws, size_t ws_size,
                              hipStream_t stream) {
    const float* x   = (const float*)d_in[0];
    const float* off = (const float*)d_in[1];
    const float* w   = (const float*)d_in[2];
    float* out = (float*)d_out;
    unsigned short* wh = (unsigned short*)d_ws;                     // 73728 B
    unsigned short* xh = (unsigned short*)((char*)d_ws + 131072);   // 3.21 MB

    hipLaunchKernelGGL(prep_kernel, dim3(392 + 144), dim3(256), 0, stream, x, w, xh, wh);
    hipLaunchKernelGGL(deform_kernel, dim3(Bn * TILES), dim3(NTHR), 0, stream,
                       xh, off, wh, out);
}

// Round 7
// 33.245 us; speedup vs baseline: 1.7554x; 1.3201x over previous
//
#include <hip/hip_runtime.h>
#include <hip/hip_fp16.h>

// DeformConv2d: x[8,64,56,56], offset[8,18,56,56], weight[64,64,3,3] -> out[8,64,56,56]
// Split pipeline: prep (NHWC fp16 x + swizzled fp16 w) -> gather (im2col v) -> MFMA GEMM.

typedef _Float16 f16x8 __attribute__((ext_vector_type(8)));
typedef float    f32x4 __attribute__((ext_vector_type(4)));

namespace {
constexpr int Bn = 8, Cn = 64, Hn = 56, Wn = 56;
constexpr int Kk = 9, OCn = 64;
constexpr int NPIX = 56 * 56;      // 3136
constexpr int CK   = Cn * Kk;      // 576
constexpr int TP   = 32;           // px per gather block
constexpr int TILES = NPIX / TP;   // 98
constexpr int XTILES = NPIX / 64;  // 49
constexpr int KSTEPS = CK / 32;    // 18
// ws layout
constexpr size_t WH2_OFF = 0;                  // 73728 B
constexpr size_t XH_OFF  = 131072;             // 3,211,264 B
constexpr size_t V_OFF   = 0x340000;           // 28,901,376 B
constexpr size_t WS_NEED = V_OFF + (size_t)Bn * XTILES * 72 * 64 * 16;
}

__device__ __forceinline__ __half2 u2h(unsigned u) {
    union { unsigned u; __half2 h; } x; x.u = u; return x.h;
}
__device__ __forceinline__ unsigned bcast_h(float f) {
    unsigned short hs = __half_as_ushort(__float2half(f));
    return (unsigned)hs * 0x10001u;
}

// prep: blocks [0,392): x NCHW fp32 -> NHWC fp16. blocks [392,536): w -> wh2 swizzled A-frag layout.
// wh2 uint4 index ((og*18+kk)*64+lane) holds w[oc=og*16+(lane&15)][kglob=kk*32+(lane>>4)*8+j],
// kglob = tap*64 + c  (tap-major K ordering).
__global__ __launch_bounds__(256) void prep_kernel(
    const float* __restrict__ x, const float* __restrict__ w,
    unsigned short* __restrict__ xh, unsigned short* __restrict__ wh2)
{
    const int tid = threadIdx.x;
    if (blockIdx.x >= 392) {
        const int i = (blockIdx.x - 392) * 256 + tid;
        if (i < OCn * CK) {
            const int j    = i & 7;
            const int lane = (i >> 3) & 63;
            const int rest = i >> 9;           // og*18 + kk
            const int og   = rest / KSTEPS;
            const int oc   = og * 16 + (lane & 15);
            const int kglob = (rest % KSTEPS) * 32 + (lane >> 4) * 8 + j;
            const int tap = kglob >> 6;
            const int c   = kglob & 63;
            wh2[i] = __half_as_ushort(__float2half(w[oc * CK + c * Kk + tap]));
        }
        return;
    }
    __shared__ unsigned short lds[64][66];
    const int b  = blockIdx.x / XTILES;
    const int t0 = (blockIdx.x % XTILES) * 64;
    const float* xb = x + (size_t)b * Cn * NPIX;
    {
        const int hw0 = (tid & 15) * 4;
        #pragma unroll
        for (int i = 0; i < 4; ++i) {
            const int c = (tid >> 4) + i * 16;
            const float4 v = *(const float4*)(xb + (size_t)c * NPIX + t0 + hw0);
            lds[hw0 + 0][c] = __half_as_ushort(__float2half(v.x));
            lds[hw0 + 1][c] = __half_as_ushort(__float2half(v.y));
            lds[hw0 + 2][c] = __half_as_ushort(__float2half(v.z));
            lds[hw0 + 3][c] = __half_as_ushort(__float2half(v.w));
        }
    }
    __syncthreads();
    {
        const int co = (tid & 7) * 8;
        #pragma unroll
        for (int i = 0; i < 2; ++i) {
            const int hw = (tid >> 3) + i * 32;
            unsigned short tmp[8] __attribute__((aligned(16)));
            #pragma unroll
            for (int j = 0; j < 8; ++j) tmp[j] = lds[hw][co + j];
            *(uint4*)(xh + ((size_t)b * NPIX + t0 + hw) * Cn + co) = *(const uint4*)tmp;
        }
    }
}

// gather: block = 32 px; unit u = (k, px, oct) oct-fastest; v[b][t64][G=tap*8+oct][px64][8] fp16.
__global__ __launch_bounds__(256, 4) void gather_kernel(
    const unsigned short* __restrict__ xh, const float* __restrict__ off,
    unsigned short* __restrict__ v)
{
    __shared__ uint4 smpw[Kk * TP];   // bilinear weights, broadcast half2
    __shared__ int4  smpa[Kk * TP];   // corner offsets pre-scaled by Cn

    const int tid = threadIdx.x;
    const int b  = blockIdx.x / TILES;
    const int p0 = (blockIdx.x % TILES) * TP;
    const unsigned short* xb = xh + (size_t)b * NPIX * Cn;
    const float* offb = off + (size_t)b * 18 * NPIX;

    for (int t = tid; t < Kk * TP; t += 256) {
        const int k  = t >> 5;
        const int px = t & 31;
        const int p  = p0 + px;
        const int oy = p / Wn, ox = p % Wn;
        const int ki = k / 3, kj = k % 3;
        const float offy = offb[(size_t)(2 * k)     * NPIX + p];
        const float offx = offb[(size_t)(2 * k + 1) * NPIX + p];
        const float py  = offy + (float)(oy - 1 + ki);
        const float pxv = offx + (float)(ox - 1 + kj);
        const float y0f = floorf(py), x0f = floorf(pxv);
        const float ty = py - y0f, tx = pxv - x0f;
        const int y0 = (int)y0f, x0 = (int)x0f;
        const int y1 = y0 + 1, x1 = x0 + 1;
        const bool vy0 = (y0 >= 0) & (y0 < Hn);
        const bool vy1 = (y1 >= 0) & (y1 < Hn);
        const bool vx0 = (x0 >= 0) & (x0 < Wn);
        const bool vx1 = (x1 >= 0) & (x1 < Wn);
        const int cy0 = min(max(y0, 0), Hn - 1);
        const int cy1 = min(max(y1, 0), Hn - 1);
        const int cx0 = min(max(x0, 0), Wn - 1);
        const int cx1 = min(max(x1, 0), Wn - 1);
        uint4 wq;
        wq.x = bcast_h((vy0 && vx0) ? (1.f - ty) * (1.f - tx) : 0.f);
        wq.y = bcast_h((vy0 && vx1) ? (1.f - ty) * tx         : 0.f);
        wq.z = bcast_h((vy1 && vx0) ? ty * (1.f - tx)         : 0.f);
        wq.w = bcast_h((vy1 && vx1) ? ty * tx                 : 0.f);
        int4 av;
        av.x = (cy0 * Wn + cx0) * Cn;
        av.y = (cy0 * Wn + cx1) * Cn;
        av.z = (cy1 * Wn + cx0) * Cn;
        av.w = (cy1 * Wn + cx1) * Cn;
        smpw[t] = wq;
        smpa[t] = av;
    }
    __syncthreads();

    // per-block v base (uint4 units): tile64 = p0>>6, px64 base = p0&32
    uint4* vb = (uint4*)v + ((size_t)(b * XTILES + (p0 >> 6)) * 72) * 64 + (p0 & 32);

    uint4 wqr[2];
    uint4 s00[2], s01[2], s10[2], s11[2];
    int   sidx[2];

    auto stage = [&](int i, int sl) {
        const int u   = tid + 256 * i;     // [0, 2304)
        const int oct = u & 7;
        const int px  = (u >> 3) & 31;
        const int k   = u >> 8;
        const int m   = k * TP + px;
        const int4 av = smpa[m];
        const int co  = oct * 8;
        wqr[sl] = smpw[m];
        s00[sl] = *(const uint4*)(xb + av.x + co);
        s01[sl] = *(const uint4*)(xb + av.y + co);
        s10[sl] = *(const uint4*)(xb + av.z + co);
        s11[sl] = *(const uint4*)(xb + av.w + co);
        sidx[sl] = (k * 8 + oct) * 64 + px;
    };
    auto finish = [&](int sl) {
        const __half2 w00 = u2h(wqr[sl].x), w01 = u2h(wqr[sl].y);
        const __half2 w10 = u2h(wqr[sl].z), w11 = u2h(wqr[sl].w);
        unsigned res[4] __attribute__((aligned(16)));
        #pragma unroll
        for (int j = 0; j < 4; ++j) {
            __half2 a = __hmul2(w00, u2h(((const unsigned*)&s00[sl])[j]));
            a = __hfma2(w01, u2h(((const unsigned*)&s01[sl])[j]), a);
            a = __hfma2(w10, u2h(((const unsigned*)&s10[sl])[j]), a);
            a = __hfma2(w11, u2h(((const unsigned*)&s11[sl])[j]), a);
            res[j] = *(const unsigned*)&a;
        }
        vb[sidx[sl]] = *(const uint4*)res;
    };

    stage(0, 0);
    stage(1, 1);
    #pragma unroll
    for (int i = 2; i < 9; ++i) {
        finish(i & 1);
        stage(i, i & 1);
    }
    finish(1);
    finish(0);
}

// gemm: block = 64 oc x 64 px, 8 waves, no LDS/barriers. A from wh2, B from v.
__global__ __launch_bounds__(512) void gemm_kernel(
    const unsigned short* __restrict__ v, const unsigned short* __restrict__ wh2,
    float* __restrict__ out)
{
    const int tid  = threadIdx.x;
    const int lane = tid & 63;
    const int w    = tid >> 6;
    const int og   = w & 3;
    const int ph2  = w >> 2;
    const int b = blockIdx.x / XTILES;
    const int t = blockIdx.x % XTILES;

    const uint4* vb = (const uint4*)v + (size_t)(b * XTILES + t) * 72 * 64;
    const uint4* ab = (const uint4*)wh2 + (size_t)og * KSTEPS * 64 + lane;
    const int hi = lane >> 4, lr = lane & 15;

    f32x4 acc0 = {0.f, 0.f, 0.f, 0.f};
    f32x4 acc1 = {0.f, 0.f, 0.f, 0.f};
    #pragma unroll
    for (int kk = 0; kk < KSTEPS; ++kk) {
        union { uint4 u; f16x8 h; } a, b0, b1;
        a.u  = ab[kk * 64];
        b0.u = vb[(kk * 4 + hi) * 64 + ph2 * 32 + lr];
        b1.u = vb[(kk * 4 + hi) * 64 + ph2 * 32 + 16 + lr];
        acc0 = __builtin_amdgcn_mfma_f32_16x16x32_f16(a.h, b0.h, acc0, 0, 0, 0);
        acc1 = __builtin_amdgcn_mfma_f32_16x16x32_f16(a.h, b1.h, acc1, 0, 0, 0);
    }
    float* ob = out + ((size_t)b * OCn + og * 16 + hi * 4) * NPIX + t * 64 + ph2 * 32 + lr;
    #pragma unroll
    for (int r = 0; r < 4; ++r) {
        ob[(size_t)r * NPIX]      = acc0[r];
        ob[(size_t)r * NPIX + 16] = acc1[r];
    }
}

// Fallback fused kernel (if ws too small for v): round-6 structure, wh2 A-layout.
__global__ __launch_bounds__(576, 6) void fused_kernel(
    const unsigned short* __restrict__ xh, const float* __restrict__ off,
    const unsigned short* __restrict__ wh2, float* __restrict__ out)
{
    __shared__ uint4 smpw[Kk * TP];
    __shared__ int4  smpa[Kk * TP];
    __shared__ __align__(16) unsigned short v_lds[72][32][8];

    const int tid = threadIdx.x;
    const int b  = blockIdx.x / TILES;
    const int p0 = (blockIdx.x % TILES) * TP;
    const unsigned short* xb = xh + (size_t)b * NPIX * Cn;
    const float* offb = off + (size_t)b * 18 * NPIX;

    if (tid < Kk * TP) {
        const int k  = tid >> 5;
        const int px = tid & 31;
        const int p  = p0 + px;
        const int oy = p / Wn, ox = p % Wn;
        const int ki = k / 3, kj = k % 3;
        const float offy = offb[(size_t)(2 * k)     * NPIX + p];
        const float offx = offb[(size_t)(2 * k + 1) * NPIX + p];
        const float py  = offy + (float)(oy - 1 + ki);
        const float pxv = offx + (float)(ox - 1 + kj);
        const float y0f = floorf(py), x0f = floorf(pxv);
        const float ty = py - y0f, tx = pxv - x0f;
        const int y0 = (int)y0f, x0 = (int)x0f;
        const int y1 = y0 + 1, x1 = x0 + 1;
        const bool vy0 = (y0 >= 0) & (y0 < Hn);
        const bool vy1 = (y1 >= 0) & (y1 < Hn);
        const bool vx0 = (x0 >= 0) & (x0 < Wn);
        const bool vx1 = (x1 >= 0) & (x1 < Wn);
        uint4 wq;
        wq.x = bcast_h((vy0 && vx0) ? (1.f - ty) * (1.f - tx) : 0.f);
        wq.y = bcast_h((vy0 && vx1) ? (1.f - ty) * tx         : 0.f);
        wq.z = bcast_h((vy1 && vx0) ? ty * (1.f - tx)         : 0.f);
        wq.w = bcast_h((vy1 && vx1) ? ty * tx                 : 0.f);
        int4 av;
        av.x = (min(max(y0, 0), Hn - 1) * Wn + min(max(x0, 0), Wn - 1)) * Cn;
        av.y = (min(max(y0, 0), Hn - 1) * Wn + min(max(x1, 0), Wn - 1)) * Cn;
        av.z = (min(max(y1, 0), Hn - 1) * Wn + min(max(x0, 0), Wn - 1)) * Cn;
        av.w = (min(max(y1, 0), Hn - 1) * Wn + min(max(x1, 0), Wn - 1)) * Cn;
        smpw[tid] = wq;
        smpa[tid] = av;
    }
    __syncthreads();
    {
        const int lane = tid & 63;
        const int g0   = tid >> 6;
        const int pxl  = lane & 15;
        const int octl = lane >> 4;
        for (int i = 0; i < 4; ++i) {
            const int g   = g0 + 9 * i;
            const int px  = pxl + (g & 1) * 16;
            const int oct = octl + ((g >> 1) & 1) * 4;
            const int k   = g >> 2;
            const int m   = k * TP + px;
            const int4 av = smpa[m];
            const uint4 wq = smpw[m];
            const int co  = oct * 8;
            const uint4 s00 = *(const uint4*)(xb + av.x + co);
            const uint4 s01 = *(const uint4*)(xb + av.y + co);
            const uint4 s10 = *(const uint4*)(xb + av.z + co);
            const uint4 s11 = *(const uint4*)(xb + av.w + co);
            const __half2 w00 = u2h(wq.x), w01 = u2h(wq.y), w10 = u2h(wq.z), w11 = u2h(wq.w);
            unsigned res[4] __attribute__((aligned(16)));
            #pragma unroll
            for (int j = 0; j < 4; ++j) {
                __half2 a = __hmul2(w00, u2h(((const unsigned*)&s00)[j]));
                a = __hfma2(w01, u2h(((const unsigned*)&s01)[j]), a);
                a = __hfma2(w10, u2h(((const unsigned*)&s10)[j]), a);
                a = __hfma2(w11, u2h(((const unsigned*)&s11)[j]), a);
                res[j] = *(const unsigned*)&a;
            }
            *(uint4*)(&v_lds[k * 8 + oct][px][0]) = *(const uint4*)res;
        }
    }
    __syncthreads();
    if (tid < 512) {
        const int lane = tid & 63;
        const int w    = tid >> 6;
        const int og   = w & 3;
        const int ph   = w >> 2;
        const int lr   = lane & 15;
        const int hi   = lane >> 4;
        const uint4* ab = (const uint4*)wh2 + (size_t)og * KSTEPS * 64 + lane;
        f32x4 acc = {0.f, 0.f, 0.f, 0.f};
        #pragma unroll
        for (int kk = 0; kk < KSTEPS; ++kk) {
            union { uint4 u; f16x8 h; } a;
            a.u = ab[kk * 64];
            const f16x8 bb = *(const f16x8*)(&v_lds[kk * 4 + hi][ph * 16 + lr][0]);
            acc = __builtin_amdgcn_mfma_f32_16x16x32_f16(a.h, bb, acc, 0, 0, 0);
        }
        float* ob = out + ((size_t)b * OCn + og * 16 + hi * 4) * NPIX + p0 + ph * 16 + lr;
        #pragma unroll
        for (int r = 0; r < 4; ++r) ob[(size_t)r * NPIX] = acc[r];
    }
}

extern "C" void kernel_launch(void* const* d_in, const int* in_sizes, int n_in,
                              void* d_out, int out_size, void* d_ws, size_t ws_size,
                              hipStream_t stream) {
    const float* x   = (const float*)d_in[0];
    const float* off = (const float*)d_in[1];
    const float* w   = (const float*)d_in[2];
    float* out = (float*)d_out;
    unsigned short* wh2 = (unsigned short*)((char*)d_ws + WH2_OFF);
    unsigned short* xh  = (unsigned short*)((char*)d_ws + XH_OFF);
    unsigned short* v   = (unsigned short*)((char*)d_ws + V_OFF);

    hipLaunchKernelGGL(prep_kernel, dim3(392 + 144), dim3(256), 0, stream, x, w, xh, wh2);
    if (ws_size >= WS_NEED) {
        hipLaunchKernelGGL(gather_kernel, dim3(Bn * TILES), dim3(256), 0, stream, xh, off, v);
        hipLaunchKernelGGL(gemm_kernel, dim3(Bn * XTILES), dim3(512), 0, stream, v, wh2, out);
    } else {
        hipLaunchKernelGGL(fused_kernel, dim3(Bn * TILES), dim3(576), 0, stream, xh, off, wh2, out);
    }
}

// Round 8
// 22.062 us; speedup vs baseline: 2.6453x; 1.5069x over previous
//
#include <hip/hip_runtime.h>
#include <hip/hip_fp16.h>

// DeformConv2d: x[8,64,56,56], offset[8,18,56,56], weight[64,64,3,3] -> out[8,64,56,56]
// prep (NHWC fp16 x + swizzled fp16 w) -> fused chunk-pipelined gather+MFMA kernel.
// K ordering is tap-major: kglob = tap*64 + c. Chunk = 3 taps (6 K-steps of 32).

typedef _Float16 f16x8 __attribute__((ext_vector_type(8)));
typedef float    f32x4 __attribute__((ext_vector_type(4)));

namespace {
constexpr int Bn = 8, Cn = 64, Hn = 56, Wn = 56;
constexpr int Kk = 9, OCn = 64;
constexpr int NPIX = 56 * 56;      // 3136
constexpr int CK   = Cn * Kk;      // 576
constexpr int TP   = 32;           // px per block
constexpr int TILES = NPIX / TP;   // 98
constexpr int XTILES = NPIX / 64;  // 49 (prep transpose tiles)
constexpr int KSTEPS = CK / 32;    // 18
}

__device__ __forceinline__ __half2 u2h(unsigned u) {
    union { unsigned u; __half2 h; } x; x.u = u; return x.h;
}
__device__ __forceinline__ unsigned bcast_h(float f) {
    unsigned short hs = __half_as_ushort(__float2half(f));
    return (unsigned)hs * 0x10001u;
}

// prep: blocks [0,392): x NCHW fp32 -> NHWC fp16. blocks [392,536): w -> wh2 A-frag layout.
// wh2 uint4 index ((og*18+kk)*64+lane) = w[oc=og*16+(lane&15)][kglob=kk*32+(lane>>4)*8+j],
// kglob = tap*64 + c.
__global__ __launch_bounds__(256) void prep_kernel(
    const float* __restrict__ x, const float* __restrict__ w,
    unsigned short* __restrict__ xh, unsigned short* __restrict__ wh2)
{
    const int tid = threadIdx.x;
    if (blockIdx.x >= 392) {
        const int i = (blockIdx.x - 392) * 256 + tid;
        if (i < OCn * CK) {
            const int j    = i & 7;
            const int lane = (i >> 3) & 63;
            const int rest = i >> 9;           // og*18 + kk
            const int og   = rest / KSTEPS;
            const int oc   = og * 16 + (lane & 15);
            const int kglob = (rest % KSTEPS) * 32 + (lane >> 4) * 8 + j;
            const int tap = kglob >> 6;
            const int c   = kglob & 63;
            wh2[i] = __half_as_ushort(__float2half(w[oc * CK + c * Kk + tap]));
        }
        return;
    }
    __shared__ unsigned short lds[64][66];
    const int b  = blockIdx.x / XTILES;
    const int t0 = (blockIdx.x % XTILES) * 64;
    const float* xb = x + (size_t)b * Cn * NPIX;
    {
        const int hw0 = (tid & 15) * 4;
        #pragma unroll
        for (int i = 0; i < 4; ++i) {
            const int c = (tid >> 4) + i * 16;
            const float4 v = *(const float4*)(xb + (size_t)c * NPIX + t0 + hw0);
            lds[hw0 + 0][c] = __half_as_ushort(__float2half(v.x));
            lds[hw0 + 1][c] = __half_as_ushort(__float2half(v.y));
            lds[hw0 + 2][c] = __half_as_ushort(__float2half(v.z));
            lds[hw0 + 3][c] = __half_as_ushort(__float2half(v.w));
        }
    }
    __syncthreads();
    {
        const int co = (tid & 7) * 8;
        #pragma unroll
        for (int i = 0; i < 2; ++i) {
            const int hw = (tid >> 3) + i * 32;
            unsigned short tmp[8] __attribute__((aligned(16)));
            #pragma unroll
            for (int j = 0; j < 8; ++j) tmp[j] = lds[hw][co + j];
            *(uint4*)(xh + ((size_t)b * NPIX + t0 + hw) * Cn + co) = *(const uint4*)tmp;
        }
    }
}

// Fused: block = 32 px x 64 oc, 256 threads. Chunk-level software pipeline:
//   stage(c+1) issue -> MFMA(c) -> blend(c+1) -> barrier, double-buffered LDS v.
__global__ __launch_bounds__(256, 4) void deform_fused(
    const unsigned short* __restrict__ xh, const float* __restrict__ off,
    const unsigned short* __restrict__ wh2, float* __restrict__ out)
{
    __shared__ uint4 smpw[Kk * TP];               // 4608 B
    __shared__ int4  smpa[Kk * TP];               // 4608 B
    __shared__ __align__(16) uint4 vbuf[2][24 * TP];   // 24576 B

    const int tid = threadIdx.x;
    const int b  = blockIdx.x / TILES;
    const int p0 = (blockIdx.x % TILES) * TP;
    const unsigned short* xb = xh + (size_t)b * NPIX * Cn;
    const float* offb = off + (size_t)b * 18 * NPIX;

    // ---- metadata: entry per (k,px), 288 entries ----
    for (int e = tid; e < Kk * TP; e += 256) {
        const int k  = e >> 5;
        const int px = e & 31;
        const int p  = p0 + px;
        const int oy = p / Wn, ox = p % Wn;
        const int ki = k / 3, kj = k % 3;
        const float offy = offb[(size_t)(2 * k)     * NPIX + p];
        const float offx = offb[(size_t)(2 * k + 1) * NPIX + p];
        const float py  = offy + (float)(oy - 1 + ki);
        const float pxv = offx + (float)(ox - 1 + kj);
        const float y0f = floorf(py), x0f = floorf(pxv);
        const float ty = py - y0f, tx = pxv - x0f;
        const int y0 = (int)y0f, x0 = (int)x0f;
        const int y1 = y0 + 1, x1 = x0 + 1;
        const bool vy0 = (y0 >= 0) & (y0 < Hn);
        const bool vy1 = (y1 >= 0) & (y1 < Hn);
        const bool vx0 = (x0 >= 0) & (x0 < Wn);
        const bool vx1 = (x1 >= 0) & (x1 < Wn);
        const int cy0 = min(max(y0, 0), Hn - 1);
        const int cy1 = min(max(y1, 0), Hn - 1);
        const int cx0 = min(max(x0, 0), Wn - 1);
        const int cx1 = min(max(x1, 0), Wn - 1);
        uint4 wq;
        wq.x = bcast_h((vy0 && vx0) ? (1.f - ty) * (1.f - tx) : 0.f);
        wq.y = bcast_h((vy0 && vx1) ? (1.f - ty) * tx         : 0.f);
        wq.z = bcast_h((vy1 && vx0) ? ty * (1.f - tx)         : 0.f);
        wq.w = bcast_h((vy1 && vx1) ? ty * tx                 : 0.f);
        int4 av;
        av.x = (cy0 * Wn + cx0) * Cn;
        av.y = (cy0 * Wn + cx1) * Cn;
        av.z = (cy1 * Wn + cx0) * Cn;
        av.w = (cy1 * Wn + cx1) * Cn;
        smpw[e] = wq;
        smpa[e] = av;
    }
    __syncthreads();

    // staged registers: 3 units/chunk, 4 corners each
    uint4 s0[3], s1[3], s2[3], s3[3], wqr[3];
    int vidx[3];

    auto stage = [&](int chunk) {
        #pragma unroll
        for (int j = 0; j < 3; ++j) {
            const int u    = tid + 256 * j;    // 0..767
            const int oct  = u & 7;
            const int px   = (u >> 3) & 31;
            const int kloc = u >> 8;           // 0..2
            const int m    = (chunk * 3 + kloc) * TP + px;
            const int4 av  = smpa[m];
            wqr[j] = smpw[m];
            const int co = oct * 8;
            s0[j] = *(const uint4*)(xb + av.x + co);
            s1[j] = *(const uint4*)(xb + av.y + co);
            s2[j] = *(const uint4*)(xb + av.z + co);
            s3[j] = *(const uint4*)(xb + av.w + co);
            vidx[j] = (kloc * 8 + oct) * TP + px;
        }
    };
    auto blend = [&](int buf) {
        #pragma unroll
        for (int j = 0; j < 3; ++j) {
            const __half2 w00 = u2h(wqr[j].x), w01 = u2h(wqr[j].y);
            const __half2 w10 = u2h(wqr[j].z), w11 = u2h(wqr[j].w);
            uint4 res;
            unsigned* rp = (unsigned*)&res;
            #pragma unroll
            for (int q = 0; q < 4; ++q) {
                __half2 a = __hmul2(w00, u2h(((const unsigned*)&s0[j])[q]));
                a = __hfma2(w01, u2h(((const unsigned*)&s1[j])[q]), a);
                a = __hfma2(w10, u2h(((const unsigned*)&s2[j])[q]), a);
                a = __hfma2(w11, u2h(((const unsigned*)&s3[j])[q]), a);
                rp[q] = *(const unsigned*)&a;
            }
            vbuf[buf][vidx[j]] = res;
        }
    };

    // GEMM ids: wave = og (16 oc) x 32 px
    const int lane = tid & 63;
    const int og   = tid >> 6;
    const int hi   = lane >> 4;
    const int lr   = lane & 15;
    const uint4* ab = (const uint4*)wh2 + (size_t)og * KSTEPS * 64 + lane;
    f32x4 acc0 = {0.f, 0.f, 0.f, 0.f};
    f32x4 acc1 = {0.f, 0.f, 0.f, 0.f};

    auto mfma_chunk = [&](int chunk, int buf) {
        #pragma unroll
        for (int kl = 0; kl < 6; ++kl) {
            union { uint4 u; f16x8 h; } a, b0, b1;
            a.u  = ab[(chunk * 6 + kl) * 64];
            b0.u = vbuf[buf][(kl * 4 + hi) * TP + lr];
            b1.u = vbuf[buf][(kl * 4 + hi) * TP + 16 + lr];
            acc0 = __builtin_amdgcn_mfma_f32_16x16x32_f16(a.h, b0.h, acc0, 0, 0, 0);
            acc1 = __builtin_amdgcn_mfma_f32_16x16x32_f16(a.h, b1.h, acc1, 0, 0, 0);
        }
    };

    stage(0);
    blend(0);
    __syncthreads();
    stage(1);              // chunk-1 loads in flight under MFMA(0)
    mfma_chunk(0, 0);
    blend(1);
    __syncthreads();
    stage(2);              // chunk-2 loads in flight under MFMA(1)
    mfma_chunk(1, 1);
    blend(0);
    __syncthreads();
    mfma_chunk(2, 0);

    // D: col(px)=lr, row(oc within 16)=hi*4+r
    float* ob = out + ((size_t)b * OCn + og * 16 + hi * 4) * NPIX + p0 + lr;
    #pragma unroll
    for (int r = 0; r < 4; ++r) {
        ob[(size_t)r * NPIX]      = acc0[r];
        ob[(size_t)r * NPIX + 16] = acc1[r];
    }
}

extern "C" void kernel_launch(void* const* d_in, const int* in_sizes, int n_in,
                              void* d_out, int out_size, void* d_ws, size_t ws_size,
                              hipStream_t stream) {
    const float* x   = (const float*)d_in[0];
    const float* off = (const float*)d_in[1];
    const float* w   = (const float*)d_in[2];
    float* out = (float*)d_out;
    unsigned short* wh2 = (unsigned short*)d_ws;                    // 73728 B
    unsigned short* xh  = (unsigned short*)((char*)d_ws + 131072);  // 3.21 MB

    hipLaunchKernelGGL(prep_kernel, dim3(392 + 144), dim3(256), 0, stream, x, w, xh, wh2);
    hipLaunchKernelGGL(deform_fused, dim3(Bn * TILES), dim3(256), 0, stream,
                       xh, off, wh2, out);
}

// Round 9
// 21.964 us; speedup vs baseline: 2.6570x; 1.0044x over previous
//
#include <hip/hip_runtime.h>
#include <hip/hip_fp16.h>

// DeformConv2d: x[8,64,56,56], offset[8,18,56,56], weight[64,64,3,3] -> out[8,64,56,56]
// prep (NHWC fp16 x + swizzled fp16 w) -> fused 1-tap-chunk depth-3 pipelined gather+MFMA.
// K ordering tap-major: kglob = tap*64 + c. Chunk = 1 tap (2 K-steps of 32).

typedef _Float16 f16x8 __attribute__((ext_vector_type(8)));
typedef float    f32x4 __attribute__((ext_vector_type(4)));

namespace {
constexpr int Bn = 8, Cn = 64, Hn = 56, Wn = 56;
constexpr int Kk = 9, OCn = 64;
constexpr int NPIX = 56 * 56;      // 3136
constexpr int CK   = Cn * Kk;      // 576
constexpr int TP   = 32;           // px per block
constexpr int TILES = NPIX / TP;   // 98
constexpr int XTILES = NPIX / 64;  // 49 (prep transpose tiles)
constexpr int KSTEPS = CK / 32;    // 18
}

__device__ __forceinline__ __half2 u2h(unsigned u) {
    union { unsigned u; __half2 h; } x; x.u = u; return x.h;
}
__device__ __forceinline__ unsigned bcast_h(float f) {
    unsigned short hs = __half_as_ushort(__float2half(f));
    return (unsigned)hs * 0x10001u;
}

// prep: blocks [0,392): x NCHW fp32 -> NHWC fp16. blocks [392,536): w -> wh2 A-frag layout.
// wh2 uint4 index ((og*18+kk)*64+lane) = w[oc=og*16+(lane&15)][kglob=kk*32+(lane>>4)*8+j],
// kglob = tap*64 + c.
__global__ __launch_bounds__(256) void prep_kernel(
    const float* __restrict__ x, const float* __restrict__ w,
    unsigned short* __restrict__ xh, unsigned short* __restrict__ wh2)
{
    const int tid = threadIdx.x;
    if (blockIdx.x >= 392) {
        const int i = (blockIdx.x - 392) * 256 + tid;
        if (i < OCn * CK) {
            const int j    = i & 7;
            const int lane = (i >> 3) & 63;
            const int rest = i >> 9;           // og*18 + kk
            const int og   = rest / KSTEPS;
            const int oc   = og * 16 + (lane & 15);
            const int kglob = (rest % KSTEPS) * 32 + (lane >> 4) * 8 + j;
            const int tap = kglob >> 6;
            const int c   = kglob & 63;
            wh2[i] = __half_as_ushort(__float2half(w[oc * CK + c * Kk + tap]));
        }
        return;
    }
    __shared__ unsigned short lds[64][66];
    const int b  = blockIdx.x / XTILES;
    const int t0 = (blockIdx.x % XTILES) * 64;
    const float* xb = x + (size_t)b * Cn * NPIX;
    {
        const int hw0 = (tid & 15) * 4;
        #pragma unroll
        for (int i = 0; i < 4; ++i) {
            const int c = (tid >> 4) + i * 16;
            const float4 v = *(const float4*)(xb + (size_t)c * NPIX + t0 + hw0);
            lds[hw0 + 0][c] = __half_as_ushort(__float2half(v.x));
            lds[hw0 + 1][c] = __half_as_ushort(__float2half(v.y));
            lds[hw0 + 2][c] = __half_as_ushort(__float2half(v.z));
            lds[hw0 + 3][c] = __half_as_ushort(__float2half(v.w));
        }
    }
    __syncthreads();
    {
        const int co = (tid & 7) * 8;
        #pragma unroll
        for (int i = 0; i < 2; ++i) {
            const int hw = (tid >> 3) + i * 32;
            unsigned short tmp[8] __attribute__((aligned(16)));
            #pragma unroll
            for (int j = 0; j < 8; ++j) tmp[j] = lds[hw][co + j];
            *(uint4*)(xh + ((size_t)b * NPIX + t0 + hw) * Cn + co) = *(const uint4*)tmp;
        }
    }
}

// Fused: block = 32 px x 64 oc, 256 threads, 1-tap chunks, depth-3 gather pipeline,
// triple-buffered LDS v, depth-1 A prefetch, one barrier per chunk.
__global__ __launch_bounds__(256, 4) void deform_fused(
    const unsigned short* __restrict__ xh, const float* __restrict__ off,
    const unsigned short* __restrict__ wh2, float* __restrict__ out)
{
    __shared__ uint4 smpw[Kk * TP];            // 4608 B
    __shared__ int4  smpa[Kk * TP];            // 4608 B
    __shared__ __align__(16) uint4 vbuf[3][8 * TP];   // 12288 B

    const int tid = threadIdx.x;
    const int b  = blockIdx.x / TILES;
    const int p0 = (blockIdx.x % TILES) * TP;
    const unsigned short* xb = xh + (size_t)b * NPIX * Cn;
    const float* offb = off + (size_t)b * 18 * NPIX;

    // ---- metadata: entry per (tap, px), 288 entries ----
    for (int e = tid; e < Kk * TP; e += 256) {
        const int k  = e >> 5;
        const int px = e & 31;
        const int p  = p0 + px;
        const int oy = p / Wn, ox = p % Wn;
        const int ki = k / 3, kj = k % 3;
        const float offy = offb[(size_t)(2 * k)     * NPIX + p];
        const float offx = offb[(size_t)(2 * k + 1) * NPIX + p];
        const float py  = offy + (float)(oy - 1 + ki);
        const float pxv = offx + (float)(ox - 1 + kj);
        const float y0f = floorf(py), x0f = floorf(pxv);
        const float ty = py - y0f, tx = pxv - x0f;
        const int y0 = (int)y0f, x0 = (int)x0f;
        const int y1 = y0 + 1, x1 = x0 + 1;
        const bool vy0 = (y0 >= 0) & (y0 < Hn);
        const bool vy1 = (y1 >= 0) & (y1 < Hn);
        const bool vx0 = (x0 >= 0) & (x0 < Wn);
        const bool vx1 = (x1 >= 0) & (x1 < Wn);
        const int cy0 = min(max(y0, 0), Hn - 1);
        const int cy1 = min(max(y1, 0), Hn - 1);
        const int cx0 = min(max(x0, 0), Wn - 1);
        const int cx1 = min(max(x1, 0), Wn - 1);
        uint4 wq;
        wq.x = bcast_h((vy0 && vx0) ? (1.f - ty) * (1.f - tx) : 0.f);
        wq.y = bcast_h((vy0 && vx1) ? (1.f - ty) * tx         : 0.f);
        wq.z = bcast_h((vy1 && vx0) ? ty * (1.f - tx)         : 0.f);
        wq.w = bcast_h((vy1 && vx1) ? ty * tx                 : 0.f);
        int4 av;
        av.x = (cy0 * Wn + cx0) * Cn;
        av.y = (cy0 * Wn + cx1) * Cn;
        av.z = (cy1 * Wn + cx0) * Cn;
        av.w = (cy1 * Wn + cx1) * Cn;
        smpw[e] = wq;
        smpa[e] = av;
    }
    __syncthreads();

    // thread -> gather unit (fixed): oct = tid&7, px = (tid>>3)&31
    const int oct = tid & 7;
    const int gpx = (tid >> 3) & 31;
    const int co  = oct * 8;

    // GEMM ids: wave = og (16 oc) x 32 px
    const int lane = tid & 63;
    const int og   = tid >> 6;
    const int hi   = lane >> 4;
    const int lr   = lane & 15;
    const uint4* ab = (const uint4*)wh2 + (size_t)og * KSTEPS * 64 + lane;

    uint4 s0[3], s1[3], s2[3], s3[3], wqr[3];   // gather staging, slot = k%3
    uint4 aF[2][2];                              // A prefetch, slot = k&1
    f32x4 acc0 = {0.f, 0.f, 0.f, 0.f};
    f32x4 acc1 = {0.f, 0.f, 0.f, 0.f};

    auto stage = [&](int k) {
        const int sl = k % 3;
        const int m  = k * TP + gpx;
        const int4 av = smpa[m];
        wqr[sl] = smpw[m];
        s0[sl] = *(const uint4*)(xb + av.x + co);
        s1[sl] = *(const uint4*)(xb + av.y + co);
        s2[sl] = *(const uint4*)(xb + av.z + co);
        s3[sl] = *(const uint4*)(xb + av.w + co);
    };
    auto loadA = [&](int k) {
        const int sl = k & 1;
        aF[sl][0] = ab[(k * 2 + 0) * 64];
        aF[sl][1] = ab[(k * 2 + 1) * 64];
    };
    auto blend = [&](int k) {
        const int sl = k % 3;
        const __half2 w00 = u2h(wqr[sl].x), w01 = u2h(wqr[sl].y);
        const __half2 w10 = u2h(wqr[sl].z), w11 = u2h(wqr[sl].w);
        uint4 res;
        unsigned* rp = (unsigned*)&res;
        #pragma unroll
        for (int q = 0; q < 4; ++q) {
            __half2 a = __hmul2(w00, u2h(((const unsigned*)&s0[sl])[q]));
            a = __hfma2(w01, u2h(((const unsigned*)&s1[sl])[q]), a);
            a = __hfma2(w10, u2h(((const unsigned*)&s2[sl])[q]), a);
            a = __hfma2(w11, u2h(((const unsigned*)&s3[sl])[q]), a);
            rp[q] = *(const unsigned*)&a;
        }
        vbuf[sl][oct * TP + gpx] = res;
    };
    auto mfma = [&](int k) {
        const int sl = k % 3;
        #pragma unroll
        for (int kl = 0; kl < 2; ++kl) {
            const int octr = kl * 4 + hi;
            union { uint4 u; f16x8 h; } a, b0, b1;
            a.u  = aF[k & 1][kl];
            b0.u = vbuf[sl][octr * TP + lr];
            b1.u = vbuf[sl][octr * TP + 16 + lr];
            acc0 = __builtin_amdgcn_mfma_f32_16x16x32_f16(a.h, b0.h, acc0, 0, 0, 0);
            acc1 = __builtin_amdgcn_mfma_f32_16x16x32_f16(a.h, b1.h, acc1, 0, 0, 0);
        }
    };

    // prologue: 3 chunks of gather in flight + A(0)
    stage(0); stage(1); stage(2);
    loadA(0);
    blend(0);
    __syncthreads();

    #pragma unroll
    for (int k = 0; k < Kk; ++k) {
        if (k < Kk - 3) stage(k + 3);     // keep 12 corner loads in flight
        if (k < Kk - 1) loadA(k + 1);     // A one chunk ahead
        if (k < Kk - 1) blend(k + 1);     // finish oldest staged -> next buffer
        mfma(k);                          // consume current buffer
        __syncthreads();
    }

    // D: col(px)=lr, row(oc within 16)=hi*4+r
    float* ob = out + ((size_t)b * OCn + og * 16 + hi * 4) * NPIX + p0 + lr;
    #pragma unroll
    for (int r = 0; r < 4; ++r) {
        ob[(size_t)r * NPIX]      = acc0[r];
        ob[(size_t)r * NPIX + 16] = acc1[r];
    }
}

extern "C" void kernel_launch(void* const* d_in, const int* in_sizes, int n_in,
                              void* d_out, int out_size, void* d_ws, size_t ws_size,
                              hipStream_t stream) {
    const float* x   = (const float*)d_in[0];
    const float* off = (const float*)d_in[1];
    const float* w   = (const float*)d_in[2];
    float* out = (float*)d_out;
    unsigned short* wh2 = (unsigned short*)d_ws;                    // 73728 B
    unsigned short* xh  = (unsigned short*)((char*)d_ws + 131072);  // 3.21 MB

    hipLaunchKernelGGL(prep_kernel, dim3(392 + 144), dim3(256), 0, stream, x, w, xh, wh2);
    hipLaunchKernelGGL(deform_fused, dim3(Bn * TILES), dim3(256), 0, stream,
                       xh, off, wh2, out);
}